// Round 1
// baseline (120.091 us; speedup 1.0000x reference)
//
#include <hip/hip_runtime.h>

#define NS   1500
#define NT   1500
#define NRR  4
#define DD   64
#define NBB  200
#define TJ   25          // j rows per LDS tile
#define JT   60          // NT / TJ
#define IT   6           // ceil(NS / 256)
#define EPS  3.0

// ---------------------------------------------------------------------------
// Main all-pairs L1 kernel.  blockIdx = (j_tile, i_tile, k).
// Each thread owns one s-row (64 floats in registers); the t-tile lives in
// LDS and is read with block-uniform j => wave-broadcast, conflict-free.
// ---------------------------------------------------------------------------
__global__ __launch_bounds__(256) void pair_loss_kernel(
    const float* __restrict__ emb_s,
    const float* __restrict__ emb_t,
    float* __restrict__ loss_all)   // [4], pre-zeroed
{
    __shared__ float4 tile[TJ * 16];
    __shared__ float  red[4];

    const int jt  = blockIdx.x;
    const int it  = blockIdx.y;
    const int k   = blockIdx.z;
    const int tid = threadIdx.x;

    // ---- stage t tile: rows [j0, j0+TJ), type k, all 64 dims ----
    const float4* t4 = (const float4*)emb_t;       // row stride 64 float4
    const int j0 = jt * TJ;
    for (int u = tid; u < TJ * 16; u += 256) {
        const int jj = u >> 4, c = u & 15;
        tile[u] = t4[(j0 + jj) * 64 + k * 16 + c];
    }

    // ---- load this thread's s row into registers ----
    const int  i     = it * 256 + tid;
    const bool valid = (i < NS);
    const int  ii    = valid ? i : (NS - 1);
    const float4* s4g = (const float4*)emb_s;
    float4 s4[16];
    #pragma unroll
    for (int c = 0; c < 16; ++c)
        s4[c] = s4g[ii * 64 + k * 16 + c];

    __syncthreads();

    // ---- accumulate sum over j-tile of sum_d |s - t| ----
    float4 acc4[4];
    #pragma unroll
    for (int a = 0; a < 4; ++a) acc4[a] = make_float4(0.f, 0.f, 0.f, 0.f);

    for (int jj = 0; jj < TJ; ++jj) {
        const float4* tr = &tile[jj * 16];
        #pragma unroll
        for (int c = 0; c < 16; ++c) {
            const float4 tv = tr[c];
            const float4 sv = s4[c];
            acc4[c & 3].x += fabsf(sv.x - tv.x);
            acc4[c & 3].y += fabsf(sv.y - tv.y);
            acc4[c & 3].z += fabsf(sv.z - tv.z);
            acc4[c & 3].w += fabsf(sv.w - tv.w);
        }
    }

    float acc = (acc4[0].x + acc4[0].y + acc4[0].z + acc4[0].w)
              + (acc4[1].x + acc4[1].y + acc4[1].z + acc4[1].w)
              + (acc4[2].x + acc4[2].y + acc4[2].z + acc4[2].w)
              + (acc4[3].x + acc4[3].y + acc4[3].z + acc4[3].w);
    if (!valid) acc = 0.f;

    // ---- wave reduce (64 lanes) then block reduce, one atomic per block ----
    #pragma unroll
    for (int off = 32; off > 0; off >>= 1)
        acc += __shfl_down(acc, off, 64);

    const int wave = tid >> 6, lane = tid & 63;
    if (lane == 0) red[wave] = acc;
    __syncthreads();
    if (tid == 0) {
        const float bsum = red[0] + red[1] + red[2] + red[3];
        atomicAdd(&loss_all[k], bsum);
    }
}

// ---------------------------------------------------------------------------
// Anchor-pair L1 sums: 200 pairs x 4 types x 64 dims.  One block, 4 waves;
// wave w handles type k=w, lane = dim.
// ---------------------------------------------------------------------------
__global__ __launch_bounds__(256) void anchor_kernel(
    const float* __restrict__ emb_s,
    const float* __restrict__ emb_t,
    const int*  __restrict__ rows,
    const int*  __restrict__ cols,
    float* __restrict__ loss_alm)   // [4]
{
    const int tid = threadIdx.x;
    const int k = tid >> 6, d = tid & 63;
    float acc = 0.f;
    for (int b = 0; b < NBB; ++b) {
        const int r = rows[b];
        const int c = cols[b];
        acc += fabsf(emb_s[(r * NRR + k) * DD + d] - emb_t[(c * NRR + k) * DD + d]);
    }
    #pragma unroll
    for (int off = 32; off > 0; off >>= 1)
        acc += __shfl_down(acc, off, 64);
    if (d == 0) loss_alm[k] = acc;
}

// ---------------------------------------------------------------------------
// Final combine (double precision; trivial cost).
// ---------------------------------------------------------------------------
__global__ void final_kernel(const float* __restrict__ loss_all,
                             const float* __restrict__ loss_alm,
                             float* __restrict__ out)
{
    const double nbB   = (double)NBB;
    const double nbNot = (double)NS * (double)NT - (double)NBB;
    const double params[4] = {0.4, 0.2, 0.2, 0.2};
    double ret = 0.0;
    for (int k = 0; k < 4; ++k) {
        const double alm    = (double)loss_alm[k];
        const double allv   = (double)loss_all[k];
        const double notalm = allv - alm;
        const double lk     = alm * nbNot + (EPS * nbNot - notalm) * nbB;
        ret += params[k] * lk;
    }
    ret = ret / (double)DD / ((double)NS * (double)NT);
    out[0] = (float)ret;
}

extern "C" void kernel_launch(void* const* d_in, const int* in_sizes, int n_in,
                              void* d_out, int out_size, void* d_ws, size_t ws_size,
                              hipStream_t stream)
{
    const float* emb_s = (const float*)d_in[0];
    const float* emb_t = (const float*)d_in[1];
    const int*   rows  = (const int*)d_in[2];
    const int*   cols  = (const int*)d_in[3];
    float* out = (float*)d_out;
    float* ws  = (float*)d_ws;           // ws[0..3]=loss_all, ws[4..7]=loss_alm

    hipMemsetAsync(ws, 0, 8 * sizeof(float), stream);

    dim3 grid(JT, IT, NRR);
    pair_loss_kernel<<<grid, 256, 0, stream>>>(emb_s, emb_t, ws);
    anchor_kernel<<<1, 256, 0, stream>>>(emb_s, emb_t, rows, cols, ws + 4);
    final_kernel<<<1, 1, 0, stream>>>(ws, ws + 4, out);
}

// Round 2
// 107.992 us; speedup vs baseline: 1.1120x; 1.1120x over previous
//
#include <hip/hip_runtime.h>

#define NS   1500
#define NT   1500
#define NRR  4
#define DD   64
#define NBB  200
#define RJ   25                 // j's held in registers per wave
#define TJB  (RJ * 4)           // 100 j's per block (4 waves)
#define JB   (NT / TJB)         // 15 j-blocks
#define TI   125                // i's staged in LDS per block
#define IB   (NS / TI)          // 12 i-blocks
#define EPS  3.0

// ---------------------------------------------------------------------------
// Fused kernel.  grid = (JB, IB, 5).
//   z in [0,4): all-pairs L1 for type k=z.  lane = d; each wave holds 25
//     t-columns in registers; s-tile streamed from LDS (1 ds_read_b32 per
//     50 VALU insts -> VALU-bound).
//   z == 4: anchor-pair partial sums, 180 blocks covering 200 pairs.
// Partials accumulate into ws[0..3] (loss_all) and ws[4..7] (loss_alm).
// ---------------------------------------------------------------------------
__global__ __launch_bounds__(256) void fused_loss_kernel(
    const float* __restrict__ emb_s,
    const float* __restrict__ emb_t,
    const int*  __restrict__ rows,
    const int*  __restrict__ cols,
    float* __restrict__ ws)     // [0..3]=loss_all, [4..7]=loss_alm (pre-zeroed)
{
    __shared__ float s_tile[TI * DD];
    __shared__ float red[4];

    const int tid  = threadIdx.x;
    const int wave = tid >> 6;
    const int lane = tid & 63;          // = d

    if (blockIdx.z == 4) {
        // ---- anchor path: bid in [0,180), pairs b = bid, bid+180 ----
        const int bid = blockIdx.y * JB + blockIdx.x;
        const int k = wave, d = lane;
        float acc = 0.f;
        for (int b = bid; b < NBB; b += JB * IB) {
            const int r = rows[b];
            const int c = cols[b];
            acc += fabsf(emb_s[(r * NRR + k) * DD + d]
                       - emb_t[(c * NRR + k) * DD + d]);
        }
        #pragma unroll
        for (int off = 32; off > 0; off >>= 1)
            acc += __shfl_down(acc, off, 64);
        if (d == 0 && acc != 0.f) atomicAdd(&ws[4 + k], acc);
        else if (d == 0 && bid < NBB) atomicAdd(&ws[4 + k], acc);
        return;
    }

    const int k  = blockIdx.z;
    const int i0 = blockIdx.y * TI;
    const int j0 = blockIdx.x * TJB + wave * RJ;

    // ---- stage s-tile [TI][64] into LDS (float4 copies) ----
    const float4* s4g = (const float4*)emb_s;   // row (i,k) base = (i*4+k)*16
    float4* st4 = (float4*)s_tile;
    for (int u = tid; u < TI * 16; u += 256) {
        const int i = u >> 4, c = u & 15;
        st4[u] = s4g[((i0 + i) * NRR + k) * 16 + c];
    }

    // ---- load 25 t-columns into registers: tj[r] = t[j0+r][k][lane] ----
    float tj[RJ];
    #pragma unroll
    for (int r = 0; r < RJ; ++r)
        tj[r] = emb_t[((j0 + r) * NRR + k) * DD + lane];

    __syncthreads();

    // ---- main: stream i from LDS, accumulate |s - t| over 25 j's ----
    float acc[8];
    #pragma unroll
    for (int a = 0; a < 8; ++a) acc[a] = 0.f;

    #pragma unroll 5
    for (int ii = 0; ii < TI; ++ii) {
        const float sv = s_tile[ii * DD + lane];
        #pragma unroll
        for (int r = 0; r < RJ; ++r)
            acc[r & 7] += fabsf(sv - tj[r]);
    }

    float a = ((acc[0] + acc[1]) + (acc[2] + acc[3]))
            + ((acc[4] + acc[5]) + (acc[6] + acc[7]));

    // ---- reduce 64 lanes (sum over d), then 4 waves, one atomic ----
    #pragma unroll
    for (int off = 32; off > 0; off >>= 1)
        a += __shfl_down(a, off, 64);
    if (lane == 0) red[wave] = a;
    __syncthreads();
    if (tid == 0)
        atomicAdd(&ws[k], (red[0] + red[1]) + (red[2] + red[3]));
}

// ---------------------------------------------------------------------------
// Final combine.
// ---------------------------------------------------------------------------
__global__ void final_kernel(const float* __restrict__ ws,
                             float* __restrict__ out)
{
    const double nbB   = (double)NBB;
    const double nbNot = (double)NS * (double)NT - (double)NBB;
    const double params[4] = {0.4, 0.2, 0.2, 0.2};
    double ret = 0.0;
    for (int k = 0; k < 4; ++k) {
        const double alm    = (double)ws[4 + k];
        const double allv   = (double)ws[k];
        const double notalm = allv - alm;
        const double lk     = alm * nbNot + (EPS * nbNot - notalm) * nbB;
        ret += params[k] * lk;
    }
    ret = ret / (double)DD / ((double)NS * (double)NT);
    out[0] = (float)ret;
}

extern "C" void kernel_launch(void* const* d_in, const int* in_sizes, int n_in,
                              void* d_out, int out_size, void* d_ws, size_t ws_size,
                              hipStream_t stream)
{
    const float* emb_s = (const float*)d_in[0];
    const float* emb_t = (const float*)d_in[1];
    const int*   rows  = (const int*)d_in[2];
    const int*   cols  = (const int*)d_in[3];
    float* out = (float*)d_out;
    float* ws  = (float*)d_ws;

    hipMemsetAsync(ws, 0, 8 * sizeof(float), stream);

    dim3 grid(JB, IB, 5);
    fused_loss_kernel<<<grid, 256, 0, stream>>>(emb_s, emb_t, rows, cols, ws);
    final_kernel<<<1, 1, 0, stream>>>(ws, out);
}